// Round 11
// baseline (419.226 us; speedup 1.0000x reference)
//
#include <hip/hip_runtime.h>

#define DEV __device__ __forceinline__

typedef float  f32x4  __attribute__((ext_vector_type(4)));
typedef __bf16 bf16x4 __attribute__((ext_vector_type(4)));
typedef __bf16 bf16x8 __attribute__((ext_vector_type(8)));

DEV unsigned short f2bf(float f) {
  unsigned u = __float_as_uint(f);
  u += 0x7fffu + ((u >> 16) & 1u);           // round-to-nearest-even
  return (unsigned short)(u >> 16);
}

DEV void cp16(const void* g, void* l) {      // async global->LDS, 16B/lane
  __builtin_amdgcn_global_load_lds((const __attribute__((address_space(1))) void*)g,
                                   (__attribute__((address_space(3))) void*)l, 16, 0, 0);
}

// ---------------- CPB MLP: table16[r][h] = 16*sigmoid(mlp(tab[r])) ----------
__global__ __launch_bounds__(64) void cpb_mlp(
    const float* __restrict__ tab, const float* __restrict__ w1,
    const float* __restrict__ b1, const float* __restrict__ w2,
    float* __restrict__ table16)
{
  int r = blockIdx.x;            // 169 rows
  int t = threadIdx.x;           // 64 lanes
  float x0 = tab[r * 2 + 0], x1 = tab[r * 2 + 1];
  float part[8];
#pragma unroll
  for (int h = 0; h < 8; ++h) part[h] = 0.f;
  for (int j = t; j < 512; j += 64) {
    float hv = fmaxf(w1[j * 2 + 0] * x0 + w1[j * 2 + 1] * x1 + b1[j], 0.f);
#pragma unroll
    for (int h = 0; h < 8; ++h) part[h] += hv * w2[h * 512 + j];
  }
#pragma unroll
  for (int h = 0; h < 8; ++h) {
    float v = part[h];
    for (int off = 32; off > 0; off >>= 1) v += __shfl_down(v, off, 64);
    if (t == 0) table16[r * 8 + h] = 16.f / (1.f + expf(-v));
  }
}

// ======= merged prep: xbf16 + weight-cvt/bias + bias64/mask64 build =========
// blocks [0,12546): X fp32->bf16 (+16 zero pad rows)
// blocks [12546,13570): weights fp32->bf16, qkv bias assembly
// blocks [13570,14722): bias64 (-1e30 pad) & mask64 (0-pad), *log2(e)
__global__ __launch_bounds__(256) void prep_all(
    const float* __restrict__ X, unsigned short* __restrict__ Xb,
    const float* __restrict__ qkv_w, const float* __restrict__ proj_w,
    const float* __restrict__ q_bias, const float* __restrict__ v_bias,
    unsigned short* __restrict__ wq, unsigned short* __restrict__ wp,
    float* __restrict__ qkvb,
    const float* __restrict__ t16, const int* __restrict__ ridx,
    const float* __restrict__ mask, float* __restrict__ bias64,
    float* __restrict__ mask64)
{
  const int b = blockIdx.x;
  if (b < 12546) {                              // ---- X convert
    size_t gid = (size_t)b * 256 + threadIdx.x;
    if (gid < 3211264) {
      const float4* xp = (const float4*)X;
      float4 f0 = xp[2 * gid], f1 = xp[2 * gid + 1];
      bf16x8 u;
      u[0] = (__bf16)f0.x; u[1] = (__bf16)f0.y; u[2] = (__bf16)f0.z; u[3] = (__bf16)f0.w;
      u[4] = (__bf16)f1.x; u[5] = (__bf16)f1.y; u[6] = (__bf16)f1.z; u[7] = (__bf16)f1.w;
      ((bf16x8*)Xb)[gid] = u;
    } else {
      bf16x8 z = {};
      ((bf16x8*)Xb)[gid] = z;                   // zero-pad rows 100352..100367
    }
  } else if (b < 13570) {                       // ---- weights + bias
    int gid = (b - 12546) * 256 + threadIdx.x;  // 262144 = 196608+65536
    if (gid < 196608) wq[gid] = f2bf(qkv_w[gid]);
    else              wp[gid - 196608] = f2bf(proj_w[gid - 196608]);
    if (gid < 768)
      qkvb[gid] = (gid < 256) ? q_bias[gid] : ((gid < 512) ? 0.f : v_bias[gid - 512]);
  } else {                                      // ---- bias64 / mask64
    const float L2E = 1.44269504f;
    int gid = (b - 13570) * 256 + threadIdx.x;  // 294912 = 32768 + 262144
    int p = gid & 4095, i = p >> 6, j = p & 63;
    bool valid = (i < 49) && (j < 49);
    if (gid < 32768) {
      int h = gid >> 12;
      bias64[gid] = valid ? t16[ridx[i * 49 + j] * 8 + h] * L2E : -1e30f;
    } else {
      int g2 = gid - 32768;
      int w = g2 >> 12;
      mask64[g2] = valid ? mask[w * 2401 + i * 49 + j] * L2E : 0.f;
    }
  }
}

// ====== FULLY FUSED: QKV GEMM + window attention + PROJ GEMM ================
// block = 1 window, 512 threads, 8 waves, wave = head. Phases:
//  1. sX stage (32 KB, kt-swizzled)            [barrier]
//  2. K/Q/V GEMMs (W hoisted to regs), S^T     [barrier: retire sX reads]
//  3. vT scatter, softmax (P in regs), PV
//  4. O*rs -> bf16 -> sOx (sX region, SAME swizzled layout as sX)  [barrier]
//  5. proj = the same do_gemm(wp, h*32) reading sOx; fp32 out stores.
// Eliminates gemm_proj + the 102 MB aows round-trip + one launch.
// launch_bounds(512,2): CUDA semantics (2nd arg = blocks/CU) -> 128-VGPR cap.
__global__ __launch_bounds__(512, 2) void qkv_attn(
    const unsigned short* __restrict__ Xb, const unsigned short* __restrict__ W,
    const unsigned short* __restrict__ Wp, const float* __restrict__ qkvb,
    const float* __restrict__ proj_b, const float* __restrict__ logit_scale,
    const float* __restrict__ bias64, const float* __restrict__ mask64,
    float* __restrict__ out)
{
  __shared__ __align__(1024) char smem[65536];
  const int t = threadIdx.x, w = t >> 6, l = t & 63, quad = l >> 4, l15 = l & 15;
  char* sX = smem;                          // [64 rows][512 B], kt-chunk swizzled
  char* vT = smem + 32768 + w * 4096;       // per-wave V^T scatter region
  const int win = blockIdx.x;               // 2048 windows
  const unsigned short* xrow = Xb + (size_t)(win * 49) * 256;
  const int h = w;                          // wave = head

  // ---- stage X window (rows >= 49 zeroed); wave w -> rows w*8 .. w*8+7 ----
  {
    const int r0 = w * 8;
    const int s = l & 31;                   // 16B slot within 512B row
#pragma unroll
    for (int seg = 0; seg < 4; ++seg) {
      const int row = r0 + 2 * seg + (l >> 5);
      if (row < 49) {
        const unsigned short* src = xrow + (size_t)row * 256
                                  + (s >> 3) * 64 + (((s & 7) ^ (row & 7)) * 8);
        cp16(src, sX + (r0 + 2 * seg) * 512);   // dest: uniform base + lane*16
      } else {
        uint4 z = {};
        *(uint4*)(sX + row * 512 + s * 16) = z;
      }
    }
  }
  __syncthreads();

  // GEMM: M=64 rows (smem, sX-layout), N=32 (global Wsrc rows), K=256.
  // All 16 W loads hoisted (one latency exposure).
  // acc[nt][mA]: lane l15 -> row mA*16+l15 ; quad*4+r -> col nt*16+quad*4+r.
  auto do_gemm = [&](const unsigned short* Wsrc, int wrb, f32x4 (&acc)[2][4]) {
    bf16x8 wreg[2][8];                      // c = kt*2+kk
#pragma unroll
    for (int nt = 0; nt < 2; ++nt) {
      const unsigned short* wr = Wsrc + (size_t)(wrb + nt * 16 + l15) * 256;
#pragma unroll
      for (int c = 0; c < 8; ++c)
        wreg[nt][c] = *(const bf16x8*)(wr + (c >> 1) * 64 + (4 * (c & 1) + quad) * 8);
    }
#pragma unroll
    for (int kt = 0; kt < 4; ++kt)
#pragma unroll
      for (int kk = 0; kk < 2; ++kk) {
        bf16x8 xf[4];
#pragma unroll
        for (int mA = 0; mA < 4; ++mA)
          xf[mA] = *(const bf16x8*)(sX + (mA * 16 + l15) * 512 + kt * 128
                                       + (((4 * kk + quad) ^ (l15 & 7)) * 16));
#pragma unroll
        for (int nt = 0; nt < 2; ++nt)
#pragma unroll
          for (int mA = 0; mA < 4; ++mA)
            acc[nt][mA] = __builtin_amdgcn_mfma_f32_16x16x32_bf16(
                wreg[nt][kt * 2 + kk], xf[mA], acc[nt][mA], 0, 0, 0);
      }
  };

  // lane-local acc(+bias) -> L2-NORMALIZED d'-fragment (norm folded pre-bf16)
  auto cvt_norm = [&](f32x4 (&acc)[2][4], const float* bias, float mul,
                      bf16x8 (&f)[4]) {
    const f32x4 b0 = *(const f32x4*)(bias + quad * 4);
    const f32x4 b1 = *(const f32x4*)(bias + 16 + quad * 4);
#pragma unroll
    for (int mt = 0; mt < 4; ++mt) {       // token mt*16+l15
      float v[8];
#pragma unroll
      for (int r = 0; r < 4; ++r) {
        v[r]     = acc[0][mt][r] + b0[r];
        v[4 + r] = acc[1][mt][r] + b1[r];
      }
      float ss = 0.f;
#pragma unroll
      for (int i = 0; i < 8; ++i) ss += v[i] * v[i];
      ss += __shfl_xor(ss, 16, 64); ss += __shfl_xor(ss, 32, 64);
      const float rn = mul / fmaxf(sqrtf(ss), 1e-12f);
#pragma unroll
      for (int i = 0; i < 8; ++i) f[mt][i] = (__bf16)(v[i] * rn);
    }
  };

  // ---- K and Q GEMMs -> normalized in-register fragments ----
  const float scale = __expf(fminf(logit_scale[h], 4.60517019f)) * 1.44269504f;
  bf16x8 kf[4], qf[4];
  {
    f32x4 ka[2][4] = {};
    do_gemm(W, 256 + h * 32, ka);
    cvt_norm(ka, qkvb + 256 + h * 32, 1.f, kf);
  }
  {
    f32x4 qa[2][4] = {};
    do_gemm(W, h * 32, qa);
    cvt_norm(qa, qkvb + h * 32, scale, qf);   // scale*log2(e) folded into q
  }

  // ---- S^T[j][i] = K . Q^T  (already scaled, log2 domain) ----
  f32x4 sacc[4][4] = {};
  __builtin_amdgcn_s_setprio(1);
#pragma unroll
  for (int mt = 0; mt < 4; ++mt)
#pragma unroll
    for (int nt = 0; nt < 4; ++nt)
      sacc[mt][nt] = __builtin_amdgcn_mfma_f32_16x16x32_bf16(kf[mt], qf[nt], sacc[mt][nt], 0, 0, 0);
  __builtin_amdgcn_s_setprio(0);

  // ---- V GEMM -> vT scatter (true-d rows, swizzled) ----
  {
    f32x4 va[2][4] = {};
    do_gemm(W, 512 + h * 32, va);
    const f32x4 vb0 = *(const f32x4*)(qkvb + 512 + h * 32 + quad * 4);
    const f32x4 vb1 = *(const f32x4*)(qkvb + 512 + h * 32 + 16 + quad * 4);
#pragma unroll
    for (int mA = 0; mA < 4; ++mA) {
      const int tok = mA * 16 + l15;
#pragma unroll
      for (int nt = 0; nt < 2; ++nt) {
#pragma unroll
        for (int r = 0; r < 4; ++r) {
          const int d = nt * 16 + quad * 4 + r;
          *(__bf16*)(vT + d * 128 + (((tok >> 3) ^ (d & 7)) << 4) + (tok & 7) * 2) =
              (__bf16)(va[nt][mA][r] + (nt ? vb1[r] : vb0[r]));
        }
      }
    }
  }
  // all waves' sX reads are retired (V GEMM was the last); sX region may be
  // overwritten with sOx after this barrier.
  __syncthreads();

  // ---- softmax (log2 domain) -> pk2 in registers ----
  const float* bh = bias64 + (size_t)h * 4096;
  const float* mw = mask64 + (size_t)(win & 63) * 4096;
  uint2 pk2[4][4];
  float rs4[4];
#pragma unroll
  for (int nt = 0; nt < 4; ++nt) {
    const int i = nt * 16 + l15;
    float mx = -3e38f;
#pragma unroll
    for (int mt = 0; mt < 4; ++mt) {
      const int jb = mt * 16 + quad * 4;
      const f32x4 b4 = *(const f32x4*)(bh + i * 64 + jb);
      const f32x4 m4 = *(const f32x4*)(mw + i * 64 + jb);
#pragma unroll
      for (int r = 0; r < 4; ++r) {
        float sv = sacc[mt][nt][r] + b4[r] + m4[r];
        sacc[mt][nt][r] = sv;
        mx = fmaxf(mx, sv);
      }
    }
    mx = fmaxf(mx, __shfl_xor(mx, 16, 64));
    mx = fmaxf(mx, __shfl_xor(mx, 32, 64));
    float sum = 0.f;
#pragma unroll
    for (int mt = 0; mt < 4; ++mt) {
      float pv[4];
#pragma unroll
      for (int r = 0; r < 4; ++r) {
        pv[r] = __builtin_amdgcn_exp2f(sacc[mt][nt][r] - mx);
        sum += pv[r];
      }
      bf16x4 pk;
      pk[0] = (__bf16)pv[0]; pk[1] = (__bf16)pv[1];
      pk[2] = (__bf16)pv[2]; pk[3] = (__bf16)pv[3];
      pk2[nt][mt] = *(uint2*)&pk;
    }
    sum += __shfl_xor(sum, 16, 64);
    sum += __shfl_xor(sum, 32, 64);
    rs4[nt] = 1.f / sum;                    // applied at sOx write
  }

  // ---- load vf (vT writes drained by the barrier above) ----
  bf16x8 vf[2][2];
#pragma unroll
  for (int kk = 0; kk < 2; ++kk)
#pragma unroll
    for (int mt = 0; mt < 2; ++mt)
      vf[kk][mt] = *(const bf16x8*)(vT + (mt * 16 + l15) * 128
                                       + (((4 * kk + quad) ^ (l15 & 7)) * 16));

  // ---- O^T[d][i] = V^T . P^T ; pf built by cross-quad shuffles ----
  const int srcA = l15 + 32 * (quad & 1);
  const bool hiSel = (quad >> 1) != 0;
  f32x4 oacc[2][4] = {};
#pragma unroll
  for (int kk = 0; kk < 2; ++kk) {
    bf16x8 pf[4];
#pragma unroll
    for (int nt = 0; nt < 4; ++nt) {
      const uint2 e = pk2[nt][2 * kk], o = pk2[nt][2 * kk + 1];
      unsigned e0 = __shfl((int)e.x, srcA, 64),      e1 = __shfl((int)e.y, srcA, 64);
      unsigned o0 = __shfl((int)o.x, srcA, 64),      o1 = __shfl((int)o.y, srcA, 64);
      unsigned e2 = __shfl((int)e.x, srcA + 16, 64), e3 = __shfl((int)e.y, srcA + 16, 64);
      unsigned o2 = __shfl((int)o.x, srcA + 16, 64), o3 = __shfl((int)o.y, srcA + 16, 64);
      uint4 u;
      u.x = hiSel ? o0 : e0; u.y = hiSel ? o1 : e1;
      u.z = hiSel ? o2 : e2; u.w = hiSel ? o3 : e3;
      pf[nt] = *(bf16x8*)&u;
    }
    __builtin_amdgcn_s_setprio(1);
#pragma unroll
    for (int mt = 0; mt < 2; ++mt)
#pragma unroll
      for (int nt = 0; nt < 4; ++nt)
        oacc[mt][nt] = __builtin_amdgcn_mfma_f32_16x16x32_bf16(vf[kk][mt], pf[nt], oacc[mt][nt], 0, 0, 0);
    __builtin_amdgcn_s_setprio(0);
  }

  // ---- O*rs -> bf16 -> sOx (sX region, sX-layout). ALL 64 rows (pad rows
  // are finite: pad bias => P=1/64 => O-pad = V-average); only tok<49 is
  // ever stored to global. col = h*32 + mt*16 + quad*4 (+r).
  {
    char* sOx = smem;
    const int ktp = h >> 1;
#pragma unroll
    for (int nt = 0; nt < 4; ++nt) {
      const int tok = nt * 16 + l15;
      const float rs = rs4[nt];
#pragma unroll
      for (int mt = 0; mt < 2; ++mt) {
        const int col = h * 32 + mt * 16 + quad * 4;
        const int cc = (col >> 3) & 7;
        bf16x4 ov;
        ov[0] = (__bf16)(oacc[mt][nt][0] * rs); ov[1] = (__bf16)(oacc[mt][nt][1] * rs);
        ov[2] = (__bf16)(oacc[mt][nt][2] * rs); ov[3] = (__bf16)(oacc[mt][nt][3] * rs);
        *(bf16x4*)(sOx + tok * 512 + ktp * 128 + ((cc ^ (tok & 7)) << 4)
                   + (quad & 1) * 8) = ov;
      }
    }
  }
  __syncthreads();                          // sOx complete, visible to all

  // ---- PROJ: same do_gemm, weights = Wp rows h*32.. (out cols), src = sOx
  f32x4 pacc[2][4] = {};
  do_gemm(Wp, h * 32, pacc);

  // ---- epilogue: add proj bias, fp32 stores (full 64B-line coverage) ----
  const f32x4 pb0 = *(const f32x4*)(proj_b + h * 32 + quad * 4);
  const f32x4 pb1 = *(const f32x4*)(proj_b + h * 32 + 16 + quad * 4);
#pragma unroll
  for (int mA = 0; mA < 4; ++mA) {
    const int tok = mA * 16 + l15;
    if (tok < 49) {
      float* orow = out + (size_t)(win * 49 + tok) * 256 + h * 32;
#pragma unroll
      for (int nt = 0; nt < 2; ++nt) {
        f32x4 v = pacc[nt][mA];
        const f32x4 pb = nt ? pb1 : pb0;
        v[0] += pb[0]; v[1] += pb[1]; v[2] += pb[2]; v[3] += pb[3];
        *(f32x4*)(orow + nt * 16 + quad * 4) = v;
      }
    }
  }
}

// ---------------------------------------------------------------------------
extern "C" void kernel_launch(void* const* d_in, const int* in_sizes, int n_in,
                              void* d_out, int out_size, void* d_ws, size_t ws_size,
                              hipStream_t stream) {
  const float* x           = (const float*)d_in[0];
  const float* mask        = (const float*)d_in[1];
  const float* qkv_w       = (const float*)d_in[2];
  const float* q_bias      = (const float*)d_in[3];
  const float* v_bias      = (const float*)d_in[4];
  const float* logit_scale = (const float*)d_in[5];
  const float* cpb_w1      = (const float*)d_in[6];
  const float* cpb_b1      = (const float*)d_in[7];
  const float* cpb_w2      = (const float*)d_in[8];
  const float* proj_w      = (const float*)d_in[9];
  const float* proj_b      = (const float*)d_in[10];
  const float* rel_tab     = (const float*)d_in[11];
  const int*   rel_idx     = (const int*)d_in[12];
  float*       out         = (float*)d_out;

  char* ws = (char*)d_ws;
  unsigned short* xbf     = (unsigned short*)(ws + 0);          // 51388416 (bf16 X + pad)
  unsigned short* wq      = (unsigned short*)(ws + 205520896);  // 393216
  unsigned short* wp      = (unsigned short*)(ws + 205914112);  // 131072
  float*          qkvb    = (float*)(ws + 206045184);           // 3072
  float*          table16 = (float*)(ws + 206048256);           // 5632
  float*          bias64  = (float*)(ws + 206053888);           // 131072
  float*          mask64  = (float*)(ws + 206184960);           // 1048576
  // end: 207233536

  cpb_mlp<<<169, 64, 0, stream>>>(rel_tab, cpb_w1, cpb_b1, cpb_w2, table16);
  prep_all<<<14722, 256, 0, stream>>>(x, xbf, qkv_w, proj_w, q_bias, v_bias,
                                      wq, wp, qkvb, table16, rel_idx, mask,
                                      bias64, mask64);
  qkv_attn<<<2048, 512, 0, stream>>>(xbf, wq, wp, qkvb, proj_b, logit_scale,
                                     bias64, mask64, out);
}